// Round 8
// baseline (131.873 us; speedup 1.0000x reference)
//
#include <hip/hip_runtime.h>
#include <math.h>

// Shapes (from setup_inputs): B=2, N=512, C=256, H=128, W=224.
#define PTS 8    // points per MLP block
#define PX 16    // pixels per splat block (14 x-tiles per row)
#define CH 16    // gaussians per weight chunk (CH*PX == 256 threads)
#define NTX 14   // tiles per row (W/PX)
#define TCAP 512 // per-tile list capacity (== N, cannot overflow)

// ---------------- kernel 1: per-gaussian projection/prep ----------------
__global__ void prep_kernel(const float* __restrict__ gd,
                            const float* __restrict__ Kmat,
                            float4* __restrict__ bbox,
                            float4* __restrict__ prm,
                            int N, int B, float Wf, float Hf) {
  int i = blockIdx.x * blockDim.x + threadIdx.x;
  if (i >= B * N) return;
  int b = i / N;
  const float* g = gd + (size_t)i * 14;
  float X = g[0], Y = g[1], Z = g[2];
  float sigx = g[5], sigy = g[6], wt = g[12];
  const float* K = Kmat + (size_t)b * 9;
  float p0 = K[0]*X + K[1]*Y + K[2]*Z;
  float p1 = K[3]*X + K[4]*Y + K[5]*Z;
  float p2 = K[6]*X + K[7]*Y + K[8]*Z;
  float denom = p2 + 1e-6f;
  float p2x = p0 / denom, p2y = p1 / denom;
  float scale_x = Wf / K[2] * 0.5f;   // W / K[0,2] / 2
  float scale_y = Hf / K[5] * 0.5f;   // H / K[1,2] / 2
  float cx = p2x * scale_x;
  float cy = p2y * scale_y;
  bool valid = Z > 0.1f;
  bool inb = (cx >= 0.f) && (cx < Wf) && (cy >= 0.f) && (cy < Hf);
  bool active = valid && inb;
  float sxv = fmaxf(sigx * scale_x, 1.f);
  float syv = fmaxf(sigy * scale_y, 1.f);
  float wn = active ? wt : 0.f;
  float avg = 0.5f * (sxv + syv);
  if (active && wn != 0.f) {
    bbox[i] = make_float4(cx, cy, 3.f * sxv, 3.f * syv);
  } else {
    bbox[i] = make_float4(-1e30f, -1e30f, 0.f, 0.f);  // never culled-in
  }
  prm[i] = make_float4(1.f / sxv, 1.f / syv, wn, avg);
}

// ---------------- kernel 2: MLP h = relu(pf@W1^T+b1)@W2^T+b2 ----------------
__global__ __launch_bounds__(256, 2) void mlp_kernel(
    const float* __restrict__ pf, const float* __restrict__ W1,
    const float* __restrict__ b1, const float* __restrict__ W2,
    const float* __restrict__ b2, float* __restrict__ hout, int npts) {
  const int t = threadIdx.x;            // output channel (C==256)
  const int p0 = blockIdx.x * PTS;
  __shared__ __align__(16) float xs[PTS][256];

  const float4* pf4 = (const float4*)(pf + (size_t)p0 * 256);
  float4* xs4 = (float4*)&xs[0][0];
  #pragma unroll
  for (int i = 0; i < PTS * 64 / 256; ++i) xs4[t + 256 * i] = pf4[t + 256 * i];
  __syncthreads();

  float acc[PTS];
  float bb1 = b1[t];
  #pragma unroll
  for (int p = 0; p < PTS; ++p) acc[p] = bb1;
  const float* w1r = W1 + (size_t)t * 256;
  for (int k = 0; k < 256; k += 4) {
    float4 w = *(const float4*)(w1r + k);
    #pragma unroll
    for (int p = 0; p < PTS; ++p) {
      float4 x = *(const float4*)(&xs[p][k]);
      acc[p] += w.x * x.x + w.y * x.y + w.z * x.z + w.w * x.w;
    }
  }
  __syncthreads();
  #pragma unroll
  for (int p = 0; p < PTS; ++p) xs[p][t] = fmaxf(acc[p], 0.f);
  __syncthreads();

  float acc2[PTS];
  float bb2 = b2[t];
  #pragma unroll
  for (int p = 0; p < PTS; ++p) acc2[p] = bb2;
  const float* w2r = W2 + (size_t)t * 256;
  for (int k = 0; k < 256; k += 4) {
    float4 w = *(const float4*)(w2r + k);
    #pragma unroll
    for (int p = 0; p < PTS; ++p) {
      float4 x = *(const float4*)(&xs[p][k]);
      acc2[p] += w.x * x.x + w.y * x.y + w.z * x.z + w.w * x.w;
    }
  }
  #pragma unroll
  for (int p = 0; p < PTS; ++p)
    if (p0 + p < npts) hout[((size_t)(p0 + p)) * 256 + t] = acc2[p];
}

// ---------------- kernel 2b: per-(row,tile) cull -----------------------------
// block = (row, b). Row-cull via ballot (ascending g), then 14 threads each
// serially split the row list into their tile's list (ascending preserved),
// then cooperative copy to global. Splat blocks get ready-made lists.
__global__ __launch_bounds__(256) void tilecull_kernel(
    const float4* __restrict__ bbox, unsigned short* __restrict__ tilelist,
    int* __restrict__ tilecnt, int N, int H, int W) {
  const int t = threadIdx.x;
  const int row = blockIdx.x;
  const int b = blockIdx.y;
  __shared__ int rowg[512];
  __shared__ unsigned short tl[NTX][TCAP];
  __shared__ int tcnt[NTX];
  __shared__ int wcnt[4];
  const float rf = (float)row;
  const float wmax = (float)(W - 1);
  const int lane = t & 63, wave = t >> 6;
  const unsigned long long lmask = (1ull << lane) - 1ull;
  const size_t bN = (size_t)b * N;

  int rowlen = 0;
  for (int gb = 0; gb < N; gb += 256) {
    int g = gb + t;
    bool f = false;
    if (g < N) {
      float4 bb = bbox[bN + g];
      f = (bb.y - bb.w <= rf) && (bb.y + bb.w >= rf) &&
          (bb.x + bb.z >= 0.f) && (bb.x - bb.z <= wmax);
    }
    unsigned long long m = __ballot(f);
    if (lane == 0) wcnt[wave] = __popcll(m);
    __syncthreads();
    int pre = 0;
    #pragma unroll
    for (int wv = 0; wv < 4; ++wv) pre += (wv < wave) ? wcnt[wv] : 0;
    int tot = wcnt[0] + wcnt[1] + wcnt[2] + wcnt[3];
    if (f) rowg[rowlen + pre + __popcll(m & lmask)] = g;
    __syncthreads();
    rowlen += tot;
  }

  // per-tile split: thread tx scans the row list (ascending order kept)
  if (t < NTX) {
    const float txlo = (float)(t * PX), txhi = (float)(t * PX + PX - 1);
    int c = 0;
    for (int i = 0; i < rowlen; ++i) {
      int g = rowg[i];
      float4 bb = bbox[bN + g];
      if (bb.x + bb.z >= txlo && bb.x - bb.z <= txhi)
        tl[t][c++] = (unsigned short)g;
    }
    tcnt[t] = c;
  }
  __syncthreads();

  // cooperative copy to global
  const size_t rbase = ((size_t)b * H + row) * NTX;
  for (int tx = 0; tx < NTX; ++tx) {
    int c = tcnt[tx];
    for (int i = t; i < c; i += 256)
      tilelist[(rbase + tx) * TCAP + i] = tl[tx][i];
  }
  if (t < NTX) tilecnt[rbase + t] = tcnt[t];
}

// ---------------- kernel 3: gather-splat, 16-px tile per block --------------
// v8: no in-block cull (tilecull provides lists); chunk pipeline issues chunk
// c+1's hv + bbox/prm loads at the TOP of chunk c's body so the barrier's
// vmcnt(0) drain lands AFTER they've had the full weight+dens+FMA phase to
// complete (v7 issued them right before the barrier -> no overlap).
__global__ __launch_bounds__(256) void splat_kernel(
    const float4* __restrict__ bbox, const float4* __restrict__ prm,
    const float* __restrict__ hfeat,
    const unsigned short* __restrict__ tilelist, const int* __restrict__ tilecnt,
    float* __restrict__ fout, float* __restrict__ unc_out,
    float* __restrict__ dens_out, int N, int C, int H, int W) {
  const int t = threadIdx.x;
  const int b = blockIdx.z;
  const int row = blockIdx.y;
  const int tx = blockIdx.x;
  const int x0 = tx * PX;
  const int HW = H * W;

  __shared__ int glist[TCAP];
  __shared__ __align__(16) float wlds[2][CH][PX];
  __shared__ __align__(16) float invd_s[PX];
  __shared__ float avgs_s[2][CH];

  const float rf = (float)row;
  const float xlo = (float)x0;
  const size_t bN = (size_t)b * N;
  const size_t tbase = ((size_t)b * H + row) * NTX + tx;
  const int cnt = tilecnt[tbase];
  const unsigned short* rl = tilelist + tbase * TCAP;

  // cooperative list load (<=2 iterations)
  for (int i = t; i < cnt; i += 256) glist[i] = rl[i];
  __syncthreads();

  float dreg = 0.f, ureg = 0.f;
  float acc[PX];
  #pragma unroll
  for (int j = 0; j < PX; ++j) acc[j] = 0.f;

  const int gi_w = t >> 4, j_w = t & 15;   // weight slot (CH x PX)
  const int nchunk = (cnt + CH - 1) / CH;

  float hvA[CH], hvB[CH];

  // weight-compute helper (into buffer BUF for chunk starting at CB)
#define WEIGHTS(BUF, CB) do { \
    float w_ = 0.f, av_ = 0.f; \
    int gcw_ = cnt - (CB); \
    if (gi_w < gcw_) { \
      int g_ = glist[(CB) + gi_w]; \
      float4 bb_ = bbox[bN + g_]; \
      float4 pr_ = prm[bN + g_]; \
      float dx_ = (xlo + (float)j_w - bb_.x) * pr_.x; \
      float dy_ = (rf - bb_.y) * pr_.y; \
      float q_ = dx_ * dx_ + dy_ * dy_; \
      w_ = (q_ < 9.f) ? __expf(-0.5f * q_) * pr_.z : 0.f; \
      av_ = pr_.w; \
    } \
    wlds[BUF][gi_w][j_w] = w_; \
    if (j_w == 0) avgs_s[BUF][gi_w] = av_; \
  } while (0)

#define HVLOAD(HV, CB) do { \
    int gch_ = cnt - (CB); \
    _Pragma("unroll") \
    for (int gi = 0; gi < CH; ++gi) \
      HV[gi] = (gi < gch_) ? hfeat[(bN + glist[(CB) + gi]) * (size_t)C + t] : 0.f; \
  } while (0)

#define FMAHALF(WR, HV, LO, HI) do { \
    _Pragma("unroll") \
    for (int gi = (LO); gi < (HI); ++gi) { \
      float4 w0 = WR[gi*4+0], w1 = WR[gi*4+1], w2 = WR[gi*4+2], w3 = WR[gi*4+3]; \
      float hv = HV[gi]; \
      acc[0]  += w0.x*hv; acc[1]  += w0.y*hv; acc[2]  += w0.z*hv; acc[3]  += w0.w*hv; \
      acc[4]  += w1.x*hv; acc[5]  += w1.y*hv; acc[6]  += w1.z*hv; acc[7]  += w1.w*hv; \
      acc[8]  += w2.x*hv; acc[9]  += w2.y*hv; acc[10] += w2.z*hv; acc[11] += w2.w*hv; \
      acc[12] += w3.x*hv; acc[13] += w3.y*hv; acc[14] += w3.z*hv; acc[15] += w3.w*hv; \
    } \
  } while (0)

  // one pipelined chunk step: consume (BUF, HVC) for chunk C, prepare
  // (BUF^1, HVN) for chunk C+1. Loads for C+1 are issued FIRST so they
  // complete during dens+FMA; the trailing barrier then costs ~nothing.
#define STEP(BUF, HVC, HVN, CCUR) do { \
    const int cb_ = (CCUR) * CH; \
    const int gc_ = min(CH, cnt - cb_); \
    HVLOAD(HVN, cb_ + CH); \
    WEIGHTS(BUF ^ 1, cb_ + CH); \
    if (t < PX) { \
      for (int gi = 0; gi < gc_; ++gi) { \
        float w = wlds[BUF][gi][t]; \
        dreg += w; \
        ureg += w * avgs_s[BUF][gi]; \
      } \
    } \
    { const float4* wr_ = (const float4*)&wlds[BUF][0][0]; \
      FMAHALF(wr_, HVC, 0, 8); \
      if (gc_ > 8) FMAHALF(wr_, HVC, 8, CH); } \
    __syncthreads(); \
  } while (0)

  if (nchunk > 0) {
    HVLOAD(hvA, 0);
    WEIGHTS(0, 0);
    __syncthreads();
    for (int c = 0; c < nchunk; c += 2) {
      STEP(0, hvA, hvB, c);
      if (c + 1 < nchunk) STEP(1, hvB, hvA, c + 1);
    }
  }

  // ---- normalize + write ----
  if (t < PX) {
    float dc = fmaxf(dreg, 1e-6f);
    float inv = 1.f / dc;
    invd_s[t] = inv;
    size_t pix = (size_t)b * HW + (size_t)row * W + x0 + t;
    dens_out[pix] = dc;
    unc_out[pix] = ureg * inv;
  }
  __syncthreads();

  float* fo = fout + ((size_t)(b * C + t)) * HW + (size_t)row * W + x0;
  const float4* iv = (const float4*)invd_s;
  float4 i0 = iv[0], i1 = iv[1], i2 = iv[2], i3 = iv[3];
  *(float4*)(fo)      = make_float4(acc[0]*i0.x,  acc[1]*i0.y,  acc[2]*i0.z,  acc[3]*i0.w);
  *(float4*)(fo + 4)  = make_float4(acc[4]*i1.x,  acc[5]*i1.y,  acc[6]*i1.z,  acc[7]*i1.w);
  *(float4*)(fo + 8)  = make_float4(acc[8]*i2.x,  acc[9]*i2.y,  acc[10]*i2.z, acc[11]*i2.w);
  *(float4*)(fo + 12) = make_float4(acc[12]*i3.x, acc[13]*i3.y, acc[14]*i3.z, acc[15]*i3.w);
}

extern "C" void kernel_launch(void* const* d_in, const int* in_sizes, int n_in,
                              void* d_out, int out_size, void* d_ws, size_t ws_size,
                              hipStream_t stream) {
  const float* pf = (const float*)d_in[0];
  const float* gd = (const float*)d_in[1];
  const float* K  = (const float*)d_in[2];
  const float* W1 = (const float*)d_in[3];
  const float* b1 = (const float*)d_in[4];
  const float* W2 = (const float*)d_in[5];
  const float* b2 = (const float*)d_in[6];

  const int B = in_sizes[2] / 9;
  const int N = in_sizes[1] / (B * 14);
  const int C = in_sizes[0] / (B * N);
  const int H = 128, W = 224;

  float4* bbox = (float4*)d_ws;
  float4* prm  = bbox + (size_t)B * N;
  float*  hfe  = (float*)(prm + (size_t)B * N);
  unsigned short* tilelist = (unsigned short*)(hfe + (size_t)B * N * C);
  int* tilecnt = (int*)(tilelist + (size_t)B * H * NTX * TCAP);

  float* out      = (float*)d_out;
  float* unc_out  = out + (size_t)B * C * H * W;
  float* dens_out = unc_out + (size_t)B * H * W;

  prep_kernel<<<dim3((B * N + 255) / 256), 256, 0, stream>>>(
      gd, K, bbox, prm, N, B, (float)W, (float)H);
  mlp_kernel<<<dim3((B * N + PTS - 1) / PTS), 256, 0, stream>>>(
      pf, W1, b1, W2, b2, hfe, B * N);
  tilecull_kernel<<<dim3(H, B), 256, 0, stream>>>(
      bbox, tilelist, tilecnt, N, H, W);
  splat_kernel<<<dim3(NTX, H, B), 256, 0, stream>>>(
      bbox, prm, hfe, tilelist, tilecnt, out, unc_out, dens_out, N, C, H, W);
}

// Round 9
// 97.789 us; speedup vs baseline: 1.3485x; 1.3485x over previous
//
#include <hip/hip_runtime.h>
#include <math.h>

// Shapes (from setup_inputs): B=2, N=512, C=256, H=128, W=224.
#define PTS 4    // points per MLP block
#define PX 16    // pixels per splat tile
#define CH 16    // gaussians per weight chunk (CH*PX == 256 threads)
#define NTX 14   // tiles per row (W/PX)

// ---------------- kernel 1: per-gaussian projection/prep ----------------
__global__ void prep_kernel(const float* __restrict__ gd,
                            const float* __restrict__ Kmat,
                            float4* __restrict__ bbox,
                            float4* __restrict__ prm,
                            int N, int B, float Wf, float Hf) {
  int i = blockIdx.x * blockDim.x + threadIdx.x;
  if (i >= B * N) return;
  int b = i / N;
  const float* g = gd + (size_t)i * 14;
  float X = g[0], Y = g[1], Z = g[2];
  float sigx = g[5], sigy = g[6], wt = g[12];
  const float* K = Kmat + (size_t)b * 9;
  float p0 = K[0]*X + K[1]*Y + K[2]*Z;
  float p1 = K[3]*X + K[4]*Y + K[5]*Z;
  float p2 = K[6]*X + K[7]*Y + K[8]*Z;
  float denom = p2 + 1e-6f;
  float p2x = p0 / denom, p2y = p1 / denom;
  float scale_x = Wf / K[2] * 0.5f;   // W / K[0,2] / 2
  float scale_y = Hf / K[5] * 0.5f;   // H / K[1,2] / 2
  float cx = p2x * scale_x;
  float cy = p2y * scale_y;
  bool valid = Z > 0.1f;
  bool inb = (cx >= 0.f) && (cx < Wf) && (cy >= 0.f) && (cy < Hf);
  bool active = valid && inb;
  float sxv = fmaxf(sigx * scale_x, 1.f);
  float syv = fmaxf(sigy * scale_y, 1.f);
  float wn = active ? wt : 0.f;
  float avg = 0.5f * (sxv + syv);
  if (active && wn != 0.f) {
    bbox[i] = make_float4(cx, cy, 3.f * sxv, 3.f * syv);
  } else {
    bbox[i] = make_float4(-1e30f, -1e30f, 0.f, 0.f);  // never culled-in
  }
  prm[i] = make_float4(1.f / sxv, 1.f / syv, wn, avg);
}

// ---------------- kernel 2: MLP h = relu(pf@W1^T+b1)@W2^T+b2 ----------------
__global__ __launch_bounds__(256) void mlp_kernel(
    const float* __restrict__ pf, const float* __restrict__ W1,
    const float* __restrict__ b1, const float* __restrict__ W2,
    const float* __restrict__ b2, float* __restrict__ hout, int npts) {
  const int t = threadIdx.x;            // output channel (C==256)
  const int p0 = blockIdx.x * PTS;
  __shared__ __align__(16) float xs[PTS][256];

  const float4* pf4 = (const float4*)(pf + (size_t)p0 * 256);
  float4* xs4 = (float4*)&xs[0][0];
  #pragma unroll
  for (int i = 0; i < PTS * 64 / 256; ++i) xs4[t + 256 * i] = pf4[t + 256 * i];
  __syncthreads();

  float acc[PTS];
  float bb1 = b1[t];
  #pragma unroll
  for (int p = 0; p < PTS; ++p) acc[p] = bb1;
  const float* w1r = W1 + (size_t)t * 256;
  for (int k = 0; k < 256; k += 4) {
    float4 w = *(const float4*)(w1r + k);
    #pragma unroll
    for (int p = 0; p < PTS; ++p) {
      float4 x = *(const float4*)(&xs[p][k]);
      acc[p] += w.x * x.x + w.y * x.y + w.z * x.z + w.w * x.w;
    }
  }
  __syncthreads();
  #pragma unroll
  for (int p = 0; p < PTS; ++p) xs[p][t] = fmaxf(acc[p], 0.f);
  __syncthreads();

  float acc2[PTS];
  float bb2 = b2[t];
  #pragma unroll
  for (int p = 0; p < PTS; ++p) acc2[p] = bb2;
  const float* w2r = W2 + (size_t)t * 256;
  for (int k = 0; k < 256; k += 4) {
    float4 w = *(const float4*)(w2r + k);
    #pragma unroll
    for (int p = 0; p < PTS; ++p) {
      float4 x = *(const float4*)(&xs[p][k]);
      acc2[p] += w.x * x.x + w.y * x.y + w.z * x.z + w.w * x.w;
    }
  }
  #pragma unroll
  for (int p = 0; p < PTS; ++p)
    if (p0 + p < npts) hout[((size_t)(p0 + p)) * 256 + t] = acc2[p];
}

// ---------------- kernel 2b: per-row y-cull (round-7, parallel ballot) ------
__global__ __launch_bounds__(256) void rowcull_kernel(
    const float4* __restrict__ bbox, unsigned short* __restrict__ rowlist,
    int* __restrict__ rowcnt, int N, int H, int W) {
  const int t = threadIdx.x;
  const int row = blockIdx.x;
  const int b = blockIdx.y;
  __shared__ int wcnt[4];
  const float rf = (float)row;
  const float wmax = (float)(W - 1);
  const int lane = t & 63, wave = t >> 6;
  const unsigned long long lmask = (1ull << lane) - 1ull;
  const size_t bN = (size_t)b * N;
  unsigned short* rl = rowlist + ((size_t)b * H + row) * N;

  int listlen = 0;
  for (int gb = 0; gb < N; gb += 256) {
    int g = gb + t;
    bool f = false;
    if (g < N) {
      float4 bb = bbox[bN + g];
      f = (bb.y - bb.w <= rf) && (bb.y + bb.w >= rf) &&
          (bb.x + bb.z >= 0.f) && (bb.x - bb.z <= wmax);
    }
    unsigned long long m = __ballot(f);
    if (lane == 0) wcnt[wave] = __popcll(m);
    __syncthreads();
    int pre = 0;
    #pragma unroll
    for (int wv = 0; wv < 4; ++wv) pre += (wv < wave) ? wcnt[wv] : 0;
    int tot = wcnt[0] + wcnt[1] + wcnt[2] + wcnt[3];
    if (f) rl[listlen + pre + __popcll(m & lmask)] = (unsigned short)g;
    __syncthreads();
    listlen += tot;
  }
  if (t == 0) rowcnt[(size_t)b * H + row] = listlen;
}

// ---------------- kernel 3: gather-splat, 16-px tile per block --------------
// v9: identical chunk engine to round 8 (in-block x-cull restored from round
// 7), but feature output goes to a TILE-CONTIGUOUS intermediate (16 KB per
// block, consecutive blocks consecutive = streaming) instead of scattering
// 64 B runs across the 114 MB [b][c][h][w] map — rounds 6-8 all plateaued at
// ~50 us = 57.8 MB / 1.2 TB/s page-thrash write ceiling.
__global__ __launch_bounds__(256) void splat_kernel(
    const float4* __restrict__ bbox, const float4* __restrict__ prm,
    const float* __restrict__ hfeat,
    const unsigned short* __restrict__ rowlist, const int* __restrict__ rowcnt,
    float* __restrict__ fout, float* __restrict__ tiled, int use_tiled,
    float* __restrict__ unc_out, float* __restrict__ dens_out,
    int N, int C, int H, int W) {
  const int t = threadIdx.x;
  const int b = blockIdx.z;
  const int row = blockIdx.y;
  const int tx = blockIdx.x;
  const int x0 = tx * PX;
  const int HW = H * W;

  __shared__ int glist[512];
  __shared__ int wcnt[4];
  __shared__ __align__(16) float wlds[2][CH][PX];
  __shared__ __align__(16) float invd_s[PX];
  __shared__ float avgs_s[2][CH];

  const float rf = (float)row;
  const float xlo = (float)x0, xhi = (float)(x0 + PX - 1);
  const int lane = t & 63, wave = t >> 6;
  const unsigned long long lmask = (1ull << lane) - 1ull;
  const size_t bN = (size_t)b * N;
  const int rcnt = rowcnt[(size_t)b * H + row];
  const unsigned short* rl = rowlist + ((size_t)b * H + row) * N;

  // ---- x-cull over the row list (ballot + cross-wave prefix, ascending) ----
  int cnt = 0;
  for (int rb = 0; rb < rcnt; rb += 256) {
    int g = 0;
    bool f = false;
    if (rb + t < rcnt) {
      g = rl[rb + t];
      float4 bb = bbox[bN + g];
      f = (bb.x + bb.z >= xlo) && (bb.x - bb.z <= xhi);
    }
    unsigned long long m = __ballot(f);
    if (lane == 0) wcnt[wave] = __popcll(m);
    __syncthreads();
    int pre = 0;
    #pragma unroll
    for (int wv = 0; wv < 4; ++wv) pre += (wv < wave) ? wcnt[wv] : 0;
    int tot = wcnt[0] + wcnt[1] + wcnt[2] + wcnt[3];
    if (f) glist[cnt + pre + __popcll(m & lmask)] = g;
    __syncthreads();
    cnt += tot;
  }

  float dreg = 0.f, ureg = 0.f;
  float acc[PX];
  #pragma unroll
  for (int j = 0; j < PX; ++j) acc[j] = 0.f;

  const int gi_w = t >> 4, j_w = t & 15;   // weight slot (CH x PX)
  const int nchunk = (cnt + CH - 1) / CH;

  float hvA[CH], hvB[CH];

#define WEIGHTS(BUF, CB) do { \
    float w_ = 0.f, av_ = 0.f; \
    int gcw_ = cnt - (CB); \
    if (gi_w < gcw_) { \
      int g_ = glist[(CB) + gi_w]; \
      float4 bb_ = bbox[bN + g_]; \
      float4 pr_ = prm[bN + g_]; \
      float dx_ = (xlo + (float)j_w - bb_.x) * pr_.x; \
      float dy_ = (rf - bb_.y) * pr_.y; \
      float q_ = dx_ * dx_ + dy_ * dy_; \
      w_ = (q_ < 9.f) ? __expf(-0.5f * q_) * pr_.z : 0.f; \
      av_ = pr_.w; \
    } \
    wlds[BUF][gi_w][j_w] = w_; \
    if (j_w == 0) avgs_s[BUF][gi_w] = av_; \
  } while (0)

#define HVLOAD(HV, CB) do { \
    int gch_ = cnt - (CB); \
    _Pragma("unroll") \
    for (int gi = 0; gi < CH; ++gi) \
      HV[gi] = (gi < gch_) ? hfeat[(bN + glist[(CB) + gi]) * (size_t)C + t] : 0.f; \
  } while (0)

#define FMAHALF(WR, HV, LO, HI) do { \
    _Pragma("unroll") \
    for (int gi = (LO); gi < (HI); ++gi) { \
      float4 w0 = WR[gi*4+0], w1 = WR[gi*4+1], w2 = WR[gi*4+2], w3 = WR[gi*4+3]; \
      float hv = HV[gi]; \
      acc[0]  += w0.x*hv; acc[1]  += w0.y*hv; acc[2]  += w0.z*hv; acc[3]  += w0.w*hv; \
      acc[4]  += w1.x*hv; acc[5]  += w1.y*hv; acc[6]  += w1.z*hv; acc[7]  += w1.w*hv; \
      acc[8]  += w2.x*hv; acc[9]  += w2.y*hv; acc[10] += w2.z*hv; acc[11] += w2.w*hv; \
      acc[12] += w3.x*hv; acc[13] += w3.y*hv; acc[14] += w3.z*hv; acc[15] += w3.w*hv; \
    } \
  } while (0)

#define STEP(BUF, HVC, HVN, CCUR) do { \
    const int cb_ = (CCUR) * CH; \
    const int gc_ = min(CH, cnt - cb_); \
    HVLOAD(HVN, cb_ + CH); \
    WEIGHTS(BUF ^ 1, cb_ + CH); \
    if (t < PX) { \
      for (int gi = 0; gi < gc_; ++gi) { \
        float w = wlds[BUF][gi][t]; \
        dreg += w; \
        ureg += w * avgs_s[BUF][gi]; \
      } \
    } \
    { const float4* wr_ = (const float4*)&wlds[BUF][0][0]; \
      FMAHALF(wr_, HVC, 0, 8); \
      if (gc_ > 8) FMAHALF(wr_, HVC, 8, CH); } \
    __syncthreads(); \
  } while (0)

  if (nchunk > 0) {
    HVLOAD(hvA, 0);
    WEIGHTS(0, 0);
    __syncthreads();
    for (int c = 0; c < nchunk; c += 2) {
      STEP(0, hvA, hvB, c);
      if (c + 1 < nchunk) STEP(1, hvB, hvA, c + 1);
    }
  }

  // ---- normalize + write ----
  if (t < PX) {
    float dc = fmaxf(dreg, 1e-6f);
    float inv = 1.f / dc;
    invd_s[t] = inv;
    size_t pix = (size_t)b * HW + (size_t)row * W + x0 + t;
    dens_out[pix] = dc;
    unc_out[pix] = ureg * inv;
  }
  __syncthreads();

  const float4* iv = (const float4*)invd_s;
  float4 i0 = iv[0], i1 = iv[1], i2 = iv[2], i3 = iv[3];
  float4 v0 = make_float4(acc[0]*i0.x,  acc[1]*i0.y,  acc[2]*i0.z,  acc[3]*i0.w);
  float4 v1 = make_float4(acc[4]*i1.x,  acc[5]*i1.y,  acc[6]*i1.z,  acc[7]*i1.w);
  float4 v2 = make_float4(acc[8]*i2.x,  acc[9]*i2.y,  acc[10]*i2.z, acc[11]*i2.w);
  float4 v3 = make_float4(acc[12]*i3.x, acc[13]*i3.y, acc[14]*i3.z, acc[15]*i3.w);

  if (use_tiled) {
    // tile-contiguous: block writes 16 KB contiguous; lane t -> t*64 B.
    float* fo = tiled + (((size_t)b * H + row) * NTX + tx) * ((size_t)C * PX)
                      + (size_t)t * PX;
    *(float4*)(fo)      = v0;
    *(float4*)(fo + 4)  = v1;
    *(float4*)(fo + 8)  = v2;
    *(float4*)(fo + 12) = v3;
  } else {
    float* fo = fout + ((size_t)(b * C + t)) * HW + (size_t)row * W + x0;
    *(float4*)(fo)      = v0;
    *(float4*)(fo + 4)  = v1;
    *(float4*)(fo + 8)  = v2;
    *(float4*)(fo + 12) = v3;
  }
}

// ---------------- kernel 4: untile (tiled -> [b][c][h][w]) ------------------
// block = (row, c-slab of 64, b); threads: t<224: cq=t/56 (4 ch sub-slabs),
// q=t%56 (px-quad). Reads 16 B/lane from tiled (L3-resident, written just
// before); writes 896 B-contiguous runs per (ch,row), rows sequential across
// concurrent blocks -> streaming HBM writes.
__global__ __launch_bounds__(256) void untile_kernel(
    const float* __restrict__ tiled, float* __restrict__ fout,
    int C, int H, int W) {
  const int t = threadIdx.x;
  if (t >= 224) return;
  const int row = blockIdx.x;
  const int cslab = blockIdx.y;
  const int b = blockIdx.z;
  const int HW = H * W;
  const int cq = t / 56;
  const int q = t - 56 * cq;
  const int tx = q >> 2;
  const int pj = (q & 3) * 4;
  const int c0 = cslab * 64 + cq * 16;

  const float* src = tiled + (((size_t)b * H + row) * NTX + tx) * ((size_t)C * PX)
                           + (size_t)c0 * PX + pj;
  float* dst = fout + ((size_t)(b * C + c0)) * HW + (size_t)row * W + q * 4;

  #pragma unroll 4
  for (int i = 0; i < 16; ++i) {
    float4 v = *(const float4*)(src + (size_t)i * PX);
    *(float4*)(dst + (size_t)i * HW) = v;
  }
}

extern "C" void kernel_launch(void* const* d_in, const int* in_sizes, int n_in,
                              void* d_out, int out_size, void* d_ws, size_t ws_size,
                              hipStream_t stream) {
  const float* pf = (const float*)d_in[0];
  const float* gd = (const float*)d_in[1];
  const float* K  = (const float*)d_in[2];
  const float* W1 = (const float*)d_in[3];
  const float* b1 = (const float*)d_in[4];
  const float* W2 = (const float*)d_in[5];
  const float* b2 = (const float*)d_in[6];

  const int B = in_sizes[2] / 9;
  const int N = in_sizes[1] / (B * 14);
  const int C = in_sizes[0] / (B * N);
  const int H = 128, W = 224;

  char* wsb = (char*)d_ws;
  size_t off = 0;
  float4* bbox = (float4*)(wsb + off); off += (size_t)B * N * sizeof(float4);
  float4* prm  = (float4*)(wsb + off); off += (size_t)B * N * sizeof(float4);
  float*  hfe  = (float*)(wsb + off);  off += (size_t)B * N * C * 4;

  const size_t tiled_bytes = (size_t)B * H * NTX * C * PX * 4;  // ~58.7 MB
  const size_t rest_bytes  = (size_t)B * H * N * 2 + 16 + (size_t)B * H * 4;
  const int use_tiled = (ws_size >= off + tiled_bytes + rest_bytes) ? 1 : 0;
  float* tiled = (float*)(wsb + off);
  if (use_tiled) off += tiled_bytes;

  unsigned short* rowlist = (unsigned short*)(wsb + off);
  off += (size_t)B * H * N * 2;
  off = (off + 15) & ~(size_t)15;
  int* rowcnt = (int*)(wsb + off);

  float* out      = (float*)d_out;
  float* unc_out  = out + (size_t)B * C * H * W;
  float* dens_out = unc_out + (size_t)B * H * W;

  prep_kernel<<<dim3((B * N + 255) / 256), 256, 0, stream>>>(
      gd, K, bbox, prm, N, B, (float)W, (float)H);
  rowcull_kernel<<<dim3(H, B), 256, 0, stream>>>(
      bbox, rowlist, rowcnt, N, H, W);
  mlp_kernel<<<dim3((B * N + PTS - 1) / PTS), 256, 0, stream>>>(
      pf, W1, b1, W2, b2, hfe, B * N);
  splat_kernel<<<dim3(NTX, H, B), 256, 0, stream>>>(
      bbox, prm, hfe, rowlist, rowcnt, out, tiled, use_tiled,
      unc_out, dens_out, N, C, H, W);
  if (use_tiled) {
    untile_kernel<<<dim3(H, C / 64, B), 256, 0, stream>>>(
        tiled, out, C, H, W);
  }
}